// Round 1
// baseline (258.118 us; speedup 1.0000x reference)
//
#include <hip/hip_runtime.h>
#include <stdint.h>
#include <math.h>

// Problem constants (match reference setup_inputs)
#define IMGF   512.0f
#define A_N    49104
#define B_N    8
#define C_N    80
#define K_N    256
#define IOU_T  0.5f
#define NBIN   4096      // linear bins: bin = (int)(score * 4096), clamped
#define CAP    2048      // per-batch candidate capacity (nc expected ~310)

__device__ __forceinline__ int bin_of(uint32_t key) {
    float s = __uint_as_float(key);          // s in [0,1)
    int b = (int)(s * 4096.0f);
    return b > 4095 ? 4095 : b;
}

// ---------------------------------------------------------------------------
// Kernel A: score + FUSED per-batch global histogram. 4 lanes per anchor,
// 5 float4 loads each (fully-consumed 64B lines per 4-lane group), 19-op fmax
// tree, 2 cross-lane shuffles, sigmoid+threshold+store+hist-atomic on lane
// j==0. Memory-bound by ~10x; the single global atomic per anchor (1/4 lanes,
// 32768 distinct L2-resident counters, ~12 adds each) hides under BW stalls.
// This removes select's entire Phase-1 (196KB key re-read + 49K LDS atomics
// per block).
// ---------------------------------------------------------------------------
__global__ __launch_bounds__(256) void score_kernel(
    const float* __restrict__ logits,
    uint32_t* __restrict__ keys,
    uint32_t* __restrict__ ghist)
{
    const int tid  = threadIdx.x;
    const int lane = tid & 63;
    const int grp  = lane >> 2, j = lane & 3;
    const int g = blockIdx.x * 64 + (tid >> 6) * 16 + grp;   // anchor (flat B*A)

    const float4* p = (const float4*)(logits + (size_t)g * C_N);
    float4 v0 = p[j], v1 = p[j + 4], v2 = p[j + 8], v3 = p[j + 12], v4 = p[j + 16];
    float m = fmaxf(fmaxf(fmaxf(v0.x, v0.y), fmaxf(v0.z, v0.w)),
                    fmaxf(fmaxf(v1.x, v1.y), fmaxf(v1.z, v1.w)));
    m = fmaxf(m, fmaxf(fmaxf(v2.x, v2.y), fmaxf(v2.z, v2.w)));
    m = fmaxf(m, fmaxf(fmaxf(v3.x, v3.y), fmaxf(v3.z, v3.w)));
    m = fmaxf(m, fmaxf(fmaxf(v4.x, v4.y), fmaxf(v4.z, v4.w)));
    m = fmaxf(m, __shfl_xor(m, 1, 64));
    m = fmaxf(m, __shfl_xor(m, 2, 64));
    if (j == 0) {
        float s = 1.0f / (1.0f + expf(-m));
        if (!(s > 0.01f)) s = 0.0f;          // reference: where(s > thr, s, 0)
        keys[g] = __float_as_uint(s);        // s >= 0 -> order-preserving bits
        int b = g / A_N;                     // compiler magic-div
        int bin = (int)(s * 4096.0f);
        if (bin > 4095) bin = 4095;
        atomicAdd(&ghist[(b << 12) + bin], 1u);
    }
}

// ---------------------------------------------------------------------------
// Kernel B (fused): one block (1024 threads) per batch.
//   1) coalesced uint4 load of precomputed 4096-bin global histogram
//   2) wave-shuffle suffix scan (2 barriers) -> exact threshold bin T
//   3) compact keys with bin >= T into LDS candidates (~310) -- the ONLY
//      full key pass now
//   4) counting-rank sort by packed (key desc, idx asc) u64 == stable top_k
//   5) decode top-256 + argmax-recovery gather (re-read 320B logit row each)
//   6) 256x256 suppression bitmask, branchless serial greedy scan == ref NMS
//   7) write dets [B,K,5] ++ labels [B,K] ++ keep [B,K] as float32
// ---------------------------------------------------------------------------
__global__ __launch_bounds__(1024) void select_nms_kernel(
    const uint32_t* __restrict__ keys,
    const uint32_t* __restrict__ ghist,
    const float* __restrict__ logits,
    const float* __restrict__ regs,
    const float* __restrict__ anchors,
    float* __restrict__ out)
{
    const int b   = blockIdx.x;
    const int tid = threadIdx.x;          // 0..1023
    const int lane = tid & 63, wv = tid >> 6;

    __shared__ int wtots[16];
    __shared__ int sh_T, sh_nc;
    __shared__ unsigned long long cand[CAP];        // 16 KB
    __shared__ unsigned long long sorted[K_N];      // 2 KB
    __shared__ float4 sbox[K_N];
    __shared__ float  sscore[K_N];
    __shared__ int    slab[K_N];
    __shared__ unsigned long long supr[K_N][4];     // 8 KB
    __shared__ unsigned long long keepw[4];

    const uint32_t* kb = keys + (size_t)b * A_N;
    const uint4* kb4 = (const uint4*)kb;            // A_N % 4 == 0, 16B aligned
    const int N4 = A_N / 4;                         // 12276

    if (tid == 0) sh_nc = 0;

    // ---- Phase 1+2: load global hist (1 uint4/thread) + threshold bin via
    //      wave-shuffle suffix scan (2 barriers) ----
    const uint4 hv = ((const uint4*)(ghist + ((size_t)b << 12)))[tid]; // bins 4t..4t+3
    const int c0 = (int)hv.x, c1 = (int)hv.y, c2 = (int)hv.z, c3 = (int)hv.w;
    const int lo = tid * 4;                         // 4 bins per thread
    int seg = c0 + c1 + c2 + c3;
    int s1 = seg;                                   // within-wave inclusive suffix
#pragma unroll
    for (int off = 1; off < 64; off <<= 1) {
        int v = __shfl_down(s1, off, 64);
        if (lane + off < 64) s1 += v;
    }
    if (lane == 0) wtots[wv] = s1;                  // wave total
    __syncthreads();
    int wsuf = 0;
    for (int w = wv + 1; w < 16; ++w) wsuf += wtots[w];
    int above = wsuf + (s1 - seg);                  // keys in strictly-later segs
    if (above < K_N && above + seg >= K_N) {        // exactly one thread true
        // walk bins hi->lo exactly like the original per-bin loop
        if      (above + c3 >= K_N)           sh_T = lo + 3;
        else if (above + c3 + c2 >= K_N)      sh_T = lo + 2;
        else if (above + c3 + c2 + c1 >= K_N) sh_T = lo + 1;
        else                                  sh_T = lo;
    }
    __syncthreads();
    const int T = sh_T;

    // ---- Phase 3: compact candidates (bin >= T) ----
    for (int i = tid; i < N4; i += 1024) {
        uint4 v = kb4[i];
        uint32_t ks[4] = { v.x, v.y, v.z, v.w };
#pragma unroll
        for (int q = 0; q < 4; ++q) {
            if (bin_of(ks[q]) >= T) {
                int p = atomicAdd(&sh_nc, 1);
                if (p < CAP)
                    cand[p] = ((unsigned long long)ks[q] << 32)
                            | (unsigned long long)(0xFFFFFFFFu - (uint32_t)(4 * i + q));
            }
        }
    }
    if (tid < K_N) sorted[tid] = 0ull;
    __syncthreads();
    int nc = sh_nc; if (nc > CAP) nc = CAP;

    // ---- Phase 4: counting-rank sort (broadcast reads, no barriers) ----
    for (int i = tid; i < nc; i += 1024) {
        unsigned long long me = cand[i];
        int r = 0;
        for (int jq = 0; jq < nc; ++jq) r += (cand[jq] > me);
        if (r < K_N) sorted[r] = me;
    }
    __syncthreads();

    // ---- Phase 5: decode top-256 + label recovery (threads 0..255) ----
    if (tid < K_N) {
#pragma clang fp contract(off)
        unsigned long long cv = sorted[tid];
        uint32_t key = (uint32_t)(cv >> 32);
        uint32_t ai  = 0xFFFFFFFFu - (uint32_t)cv;
        if (ai >= (uint32_t)A_N) ai = 0;   // pad entries (score 0, unkept)
        int a = (int)ai;
        float s = __uint_as_float(key);
        sscore[tid] = s;

        // argmax recovery: first index of max over the 80-logit row
        {
            const float4* lp = (const float4*)(logits + ((size_t)b * A_N + a) * C_N);
            float best = -INFINITY; int cls = 0;
#pragma unroll
            for (int k = 0; k < 20; ++k) {
                float4 w = lp[k];
                if (w.x > best) { best = w.x; cls = 4 * k + 0; }
                if (w.y > best) { best = w.y; cls = 4 * k + 1; }
                if (w.z > best) { best = w.z; cls = 4 * k + 2; }
                if (w.w > best) { best = w.w; cls = 4 * k + 3; }
            }
            slab[tid] = cls;
        }

        float4 av = ((const float4*)anchors)[a];
        float ax0 = av.x, ay0 = av.y, ax1 = av.z, ay1 = av.w;
        float aw = ax1 - ax0, ah = ay1 - ay0;
        float acx = ax0 + 0.5f * aw, acy = ay0 + 0.5f * ah;
        float4 rv = ((const float4*)regs)[(size_t)b * A_N + a];
        float dx = rv.x, dy = rv.y, dw = rv.z, dh = rv.w;
        float cx = acx + dx * aw;
        float cy = acy + dy * ah;
        dw = fminf(fmaxf(dw, -4.0f), 4.0f);
        dh = fminf(fmaxf(dh, -4.0f), 4.0f);
        float w = aw * expf(dw);
        float h = ah * expf(dh);
        float x0 = cx - 0.5f * w, y0 = cy - 0.5f * h;
        float x1 = cx + 0.5f * w, y1 = cy + 0.5f * h;
        x0 = fminf(fmaxf(x0, 0.0f), IMGF);
        y0 = fminf(fmaxf(y0, 0.0f), IMGF);
        x1 = fminf(fmaxf(x1, 0.0f), IMGF);
        y1 = fminf(fmaxf(y1, 0.0f), IMGF);
        sbox[tid] = make_float4(x0, y0, x1, y1);
    }
    __syncthreads();

    // ---- Phase 6a: suppression matrix, one u64 word per thread ----
    {
#pragma clang fp contract(off)
        const int row = tid & 255, gq = tid >> 8;   // word gq of row
        float4 bi = sbox[row];
        float areai = fmaxf(bi.z - bi.x, 0.0f) * fmaxf(bi.w - bi.y, 0.0f);
        unsigned long long m = 0;
        const int jlo = gq * 64, jhi = jlo + 64;
        int start = row + 1 > jlo ? row + 1 : jlo;
        for (int jx = start; jx < jhi; ++jx) {
            float4 bj = sbox[jx];
            float areaj = fmaxf(bj.z - bj.x, 0.0f) * fmaxf(bj.w - bj.y, 0.0f);
            float lx = fmaxf(bi.x, bj.x), ly = fmaxf(bi.y, bj.y);
            float rx = fminf(bi.z, bj.z), ry = fminf(bi.w, bj.w);
            float iw = fmaxf(rx - lx, 0.0f), ih = fmaxf(ry - ly, 0.0f);
            float inter = iw * ih;
            float uni = areai + areaj - inter;
            float iou = inter / fmaxf(uni, 1e-8f);
            if (iou > IOU_T) m |= 1ull << (jx & 63);
        }
        supr[row][gq] = m;
    }
    // keep0 = score > 0 (threads 0..255 = waves 0..3)
    if (tid < K_N) {
        unsigned long long ball = __ballot(sscore[tid] > 0.0f);
        if ((tid & 63) == 0) keepw[tid >> 6] = ball;
    }
    __syncthreads();

    // ---- Phase 6b: branchless serial greedy scan (loads hoisted) ----
    if (tid == 0) {
        unsigned long long k0 = keepw[0], k1 = keepw[1], k2 = keepw[2], k3 = keepw[3];
#define NMS_CHUNK(c, kc)                                                     \
        for (int l = 0; l < 64; ++l) {                                       \
            const int i = (c) * 64 + l;                                      \
            unsigned long long w0 = supr[i][0], w1 = supr[i][1];             \
            unsigned long long w2 = supr[i][2], w3 = supr[i][3];             \
            if ((kc >> l) & 1ull) {                                          \
                k0 &= ~w0; k1 &= ~w1; k2 &= ~w2; k3 &= ~w3;                  \
            }                                                                \
        }
        NMS_CHUNK(0, k0)
        NMS_CHUNK(1, k1)
        NMS_CHUNK(2, k2)
        NMS_CHUNK(3, k3)
#undef NMS_CHUNK
        keepw[0] = k0; keepw[1] = k1; keepw[2] = k2; keepw[3] = k3;
    }
    __syncthreads();

    // ---- Phase 7: outputs: dets [B,K,5] ++ labels [B,K] ++ keep [B,K] ----
    if (tid < K_N) {
        float keepf = ((keepw[tid >> 6] >> (tid & 63)) & 1ull) ? 1.0f : 0.0f;
        float4 bx = sbox[tid];
        float s = sscore[tid];
        float* det = out + ((size_t)b * K_N + tid) * 5;
        det[0] = bx.x * keepf;
        det[1] = bx.y * keepf;
        det[2] = bx.z * keepf;
        det[3] = bx.w * keepf;
        det[4] = s * keepf;
        out[(size_t)B_N * K_N * 5 + (size_t)b * K_N + tid] = (float)slab[tid];
        out[(size_t)B_N * K_N * 5 + (size_t)B_N * K_N + (size_t)b * K_N + tid] = keepf;
    }
}

extern "C" void kernel_launch(void* const* d_in, const int* in_sizes, int n_in,
                              void* d_out, int out_size, void* d_ws, size_t ws_size,
                              hipStream_t stream)
{
    const float* logits  = (const float*)d_in[0];   // [B,A,C] fp32
    const float* regs    = (const float*)d_in[1];   // [B,A,4] fp32
    const float* anchors = (const float*)d_in[2];   // [A,4]   fp32
    float* out = (float*)d_out;

    uint32_t* keys  = (uint32_t*)d_ws;                      // B*A u32
    uint32_t* ghist = keys + (size_t)B_N * A_N;             // B*4096 u32 (16B-aligned)

    // zero the fused histogram (ws is poisoned each iteration)
    hipMemsetAsync(ghist, 0, (size_t)B_N * NBIN * sizeof(uint32_t), stream);

    const int total = B_N * A_N;                    // 392832 = 6138 * 64
    score_kernel<<<total / 64, 256, 0, stream>>>(logits, keys, ghist);
    select_nms_kernel<<<B_N, 1024, 0, stream>>>(keys, ghist, logits, regs, anchors, out);
}